// Round 11
// baseline (446.839 us; speedup 1.0000x reference)
//
#include <hip/hip_runtime.h>
#include <hip/hip_bf16.h>
#include <math.h>

#define CIN 256
#define COUT 256
#define NB 2
#define GN_GROUPS 16

typedef __attribute__((ext_vector_type(8))) short short8;
typedef __attribute__((ext_vector_type(4))) float floatx4;

__device__ __forceinline__ float b2f(unsigned short u) {
  union { unsigned int i; float f; } v;
  v.i = ((unsigned int)u) << 16;
  return v.f;
}
__device__ __forceinline__ unsigned short f2b(float f) {
  union { float f; unsigned int i; } v;
  v.f = f;
  unsigned int r = (v.i + 0x7FFFu + ((v.i >> 16) & 1u)) >> 16;
  return (unsigned short)r;
}
__device__ __forceinline__ float lo2f(unsigned int u) {
  union { unsigned int i; float f; } v;
  v.i = u << 16;
  return v.f;
}
__device__ __forceinline__ float hi2f(unsigned int u) {
  union { unsigned int i; float f; } v;
  v.i = u & 0xffff0000u;
  return v.f;
}
__device__ __forceinline__ unsigned int pk2(float a, float b) {
  union { __hip_bfloat162 h; unsigned int u; } v;
  v.h = __float22bfloat162_rn(float2{a, b});
  return v.u;
}

// ---------------------------------------------------------------------------
// Setup: NCHW->NHWC split-bf16 transpose (all levels) + mdconv weight repack
// (fragment-stream) + offset-conv weight repack + stats zeroing.
// One launch, block-range dispatch. Grid = 2688 + 6912 + 576 + 43 = 10219.
// ---------------------------------------------------------------------------
struct SetB {
  const float *x0, *x1, *x2, *wm, *wl, *wh, *wof;
  unsigned short *t0, *t1, *t2, *l0, *l1, *l2;
  unsigned short *wtm, *wtl, *wth, *wo;
  float* stats;  // 10752 floats
};

__global__ __launch_bounds__(256) void setup_kernel(SetB A) {
  __shared__ float tile[64][65];
  int bx = blockIdx.x, t = threadIdx.x;
  if (bx < 2688) {
    // ---- transpose: decode original dim3(336,4,NB) ----
    int xg = bx % 336;
    int rem = bx / 336;
    int yg = rem & 3, zg = rem >> 2;
    int li = (xg >= 256 ? 1 : 0) + (xg >= 320 ? 1 : 0);
    int local = xg - (li == 0 ? 0 : (li == 1 ? 256 : 320));
    const float* x = li == 0 ? A.x0 : (li == 1 ? A.x1 : A.x2);
    unsigned short* xT = li == 0 ? A.t0 : (li == 1 ? A.t1 : A.t2);
    unsigned short* xLo = li == 0 ? A.l0 : (li == 1 ? A.l1 : A.l2);
    int P = li == 0 ? 16384 : (li == 1 ? 4096 : 1024);
    int pBase = local * 64, cBase = yg * 64, b = zg;
    int pl = t & 63, ch = t >> 6;
    const float* xb = x + ((size_t)b * CIN + cBase) * P + pBase;
#pragma unroll
    for (int e = 0; e < 16; e++) {
      int c = ch * 16 + e;
      tile[c][pl] = xb[(size_t)c * P + pl];
    }
    __syncthreads();
    size_t obase = ((size_t)b * P + pBase) * CIN + cBase;
    int cl = t & 63, pr = t >> 6;
#pragma unroll
    for (int e = 0; e < 16; e++) {
      int p = pr * 16 + e;
      float v = tile[cl][p];
      unsigned short h = f2b(v);
      xT[obase + (size_t)p * CIN + cl] = h;
      xLo[obase + (size_t)p * CIN + cl] = f2b(v - b2f(h));
    }
  } else if (bx < 9600) {
    // ---- mdconv weight repack: fragment-stream wtf[kc][wv][i][lane][8] ----
    int lb = bx - 2688;
    int sel = (lb >= 2304 ? 1 : 0) + (lb >= 4608 ? 1 : 0);
    const float* w = sel == 0 ? A.wm : (sel == 1 ? A.wl : A.wh);
    unsigned short* wt = sel == 0 ? A.wtm : (sel == 1 ? A.wtl : A.wth);
    int idx = (lb - sel * 2304) * 256 + t;  // 589824 = 72*8192
    int e = idx & 7;
    int lane = (idx >> 3) & 63;
    int i = (idx >> 9) & 3;
    int wv = (idx >> 11) & 3;
    int kc = idx >> 13;  // 0..71
    int oc = wv * 64 + i * 16 + (lane & 15);
    int c = (kc & 7) * 32 + (lane >> 4) * 8 + e;
    int tap = kc >> 3;
    wt[idx] = f2b(w[(size_t)oc * 2304 + c * 9 + tap]);
  } else if (bx < 10176) {
    // ---- offset-conv weight repack: wo[sel][tap][cb][oc32][ch32] ----
    int idx = (bx - 9600) * 256 + t;  // 2*73728
    int sel = idx / 73728;
    int r = idx % 73728;
    int k = r / 8192;
    int r2 = r % 8192;
    int cbk = r2 / 1024;
    int oc = (r2 / 32) % 32;
    int ch = r2 % 32;
    int c = cbk * 32 + ch;
    float val = (oc < 27) ? A.wof[(size_t)oc * 2304 + c * 9 + k] : 0.0f;
    float hi = b2f(f2b(val));
    A.wo[idx] = sel ? f2b(val - hi) : f2b(val);
  } else {
    // ---- zero stats ----
    int idx = (bx - 10176) * 256 + t;
    if (idx < 10752) A.stats[idx] = 0.f;
  }
}

// ---------------------------------------------------------------------------
// Offset conv: halo-staged LDS + MFMA, split-bf16, batched over levels.
// ---------------------------------------------------------------------------
struct CoL {
  const unsigned short* xhi;
  const unsigned short* xlo;
  float* om;
  int H, W, Cs, cshift, Rs, P;
};
struct CoB { CoL L[3]; int off[4]; };

__global__ __launch_bounds__(256) void conv_offset_kernel(
    CoB B, const unsigned short* __restrict__ wo,
    const float* __restrict__ bias) {
  __shared__ unsigned short s_hi[204 * 40];
  __shared__ unsigned short s_lo[204 * 40];
  int bx = blockIdx.x;
  int li = (bx >= B.off[1] ? 1 : 0) + (bx >= B.off[2] ? 1 : 0);
  CoL L = B.L[li];
  int local = bx - B.off[li];
  int tpb = L.P / 64;
  int b = local / tpb, pxt = local % tpb;
  int t = threadIdx.x;
  int pbase = pxt * 64;
  int r0 = pbase / L.W;
  int c0 = pbase % L.W;
  int Ct = L.Cs + 2;
  int Npos = Ct * (L.Rs + 2);
  const unsigned short* xhib = L.xhi + (size_t)b * L.P * CIN;
  const unsigned short* xlob = L.xlo + (size_t)b * L.P * CIN;

  int lane = t & 63, wv = t >> 6, quad = lane >> 4, ln = lane & 15;
  int pl = wv * 16 + ln;
  int pi_ = pl >> L.cshift;
  int pj_ = pl & (L.Cs - 1);

  floatx4 acc0 = {0.f, 0.f, 0.f, 0.f}, acc1 = {0.f, 0.f, 0.f, 0.f};

  for (int cb = 0; cb < 8; cb++) {
    __syncthreads();
    for (int e = t; e < Npos * 4; e += 256) {
      int pos = e >> 2, oct = e & 3;
      int r = pos / Ct, c = pos % Ct;
      int gy = r0 - 1 + r, gx = c0 - 1 + c;
      uint4 vhi = {0, 0, 0, 0}, vlo = {0, 0, 0, 0};
      if (gy >= 0 && gy < L.H && gx >= 0 && gx < L.W) {
        size_t off = ((size_t)(gy * L.W + gx)) * CIN + cb * 32 + oct * 8;
        vhi = *(const uint4*)(xhib + off);
        vlo = *(const uint4*)(xlob + off);
      }
      *(uint4*)&s_hi[pos * 40 + oct * 8] = vhi;
      *(uint4*)&s_lo[pos * 40 + oct * 8] = vlo;
    }
    __syncthreads();
#pragma unroll
    for (int tap = 0; tap < 9; tap++) {
      int dy = tap / 3 - 1, dx = tap % 3 - 1;
      const unsigned short* wb0 = wo + (size_t)((0 * 9 + tap) * 8 + cb) * 1024;
      const unsigned short* wb1 = wo + (size_t)((1 * 9 + tap) * 8 + cb) * 1024;
      short8 whi0 = *(const short8*)(wb0 + ln * 32 + quad * 8);
      short8 whi1 = *(const short8*)(wb0 + (16 + ln) * 32 + quad * 8);
      short8 wlo0 = *(const short8*)(wb1 + ln * 32 + quad * 8);
      short8 wlo1 = *(const short8*)(wb1 + (16 + ln) * 32 + quad * 8);
      int pos = (pi_ + dy + 1) * Ct + (pj_ + dx + 1);
      short8 bhi = *(const short8*)&s_hi[pos * 40 + quad * 8];
      short8 blo = *(const short8*)&s_lo[pos * 40 + quad * 8];
      acc0 = __builtin_amdgcn_mfma_f32_16x16x32_bf16(whi0, bhi, acc0, 0, 0, 0);
      acc1 = __builtin_amdgcn_mfma_f32_16x16x32_bf16(whi1, bhi, acc1, 0, 0, 0);
      acc0 = __builtin_amdgcn_mfma_f32_16x16x32_bf16(wlo0, bhi, acc0, 0, 0, 0);
      acc1 = __builtin_amdgcn_mfma_f32_16x16x32_bf16(wlo1, bhi, acc1, 0, 0, 0);
      acc0 = __builtin_amdgcn_mfma_f32_16x16x32_bf16(whi0, blo, acc0, 0, 0, 0);
      acc1 = __builtin_amdgcn_mfma_f32_16x16x32_bf16(whi1, blo, acc1, 0, 0, 0);
    }
  }

  int px = pbase + pl;
#pragma unroll
  for (int i2 = 0; i2 < 2; i2++) {
#pragma unroll
    for (int r = 0; r < 4; r++) {
      int oc = i2 * 16 + quad * 4 + r;
      if (oc < 27) {
        float val = (i2 == 0 ? acc0[r] : acc1[r]) + bias[oc];
        if (oc >= 18) val = 1.f / (1.f + __expf(-val));
        L.om[((size_t)b * 27 + oc) * L.P + px] = val;
      }
    }
  }
}

// ---------------------------------------------------------------------------
// Modulated deformable conv v14: 128-px tiles, (256,2), SINGLE residency
// round (496 blocks <= 512 slots). The 72-chunk K-loop / 36 barrier groups
// are tile-width-independent, so doubling the tile halves block count at
// sub-2x block time -> tests the 2-round-quantization hypothesis from R10.
// Regs: 128 acc + ~64 gather + 16 af + misc ~= 233 <= 256 budget at 8
// waves/CU. LDS 69KB x2 = 138KB. Spill tripwire: WRITE_SIZE >> 72MB.
// ---------------------------------------------------------------------------
struct MdP {
  const unsigned short* xT;
  const unsigned short* wt;
  float* outf;
  const float* om;
  float* sum;
  float* sumsq;
  float* wsum;  // non-null for high path
  int Hi, Wi, Wo, lWo, stride, omStep, omW, omP, ltile, Hro;
};
struct MdBatch { MdP p[7]; int off[7]; };

#define GATHER1(k, Gp, PX)                                                  \
  do {                                                                      \
    int tap_ = (k) >> 3, cbk_ = (k) & 7;                                    \
    int yy_ = s_yy[tap_][PX], xx_ = s_xx[tap_][PX];                         \
    int y0_ = yy_ & 0xffff, y1_ = (yy_ >> 16) & 0xffff;                     \
    int x0_ = xx_ & 0xffff, x1_ = (xx_ >> 16) & 0xffff;                     \
    const unsigned short* gb_ = xTb + cbk_ * 32 + goct * 8;                 \
    (Gp)[0] = *(const uint4*)(gb_ + (size_t)(y0_ + x0_) * CIN);             \
    (Gp)[1] = *(const uint4*)(gb_ + (size_t)(y0_ + x1_) * CIN);             \
    (Gp)[2] = *(const uint4*)(gb_ + (size_t)(y1_ + x0_) * CIN);             \
    (Gp)[3] = *(const uint4*)(gb_ + (size_t)(y1_ + x1_) * CIN);             \
  } while (0)

#define PACK1(k, Gp, PX)                                                    \
  do {                                                                      \
    float4 cw_ = s_cw[(k) >> 3][PX];                                        \
    float r_[8];                                                            \
    _Pragma("unroll") for (int j_ = 0; j_ < 4; j_++) {                      \
      unsigned int a_ = ((unsigned int*)&(Gp)[0])[j_];                      \
      unsigned int b2_ = ((unsigned int*)&(Gp)[1])[j_];                     \
      unsigned int c_ = ((unsigned int*)&(Gp)[2])[j_];                      \
      unsigned int d_ = ((unsigned int*)&(Gp)[3])[j_];                      \
      r_[2 * j_] = cw_.x * lo2f(a_) + cw_.y * lo2f(b2_) +                   \
                   cw_.z * lo2f(c_) + cw_.w * lo2f(d_);                     \
      r_[2 * j_ + 1] = cw_.x * hi2f(a_) + cw_.y * hi2f(b2_) +               \
                       cw_.z * hi2f(c_) + cw_.w * hi2f(d_);                 \
    }                                                                       \
    uint4 pk_;                                                              \
    pk_.x = pk2(r_[0], r_[1]);                                              \
    pk_.y = pk2(r_[2], r_[3]);                                              \
    pk_.z = pk2(r_[4], r_[5]);                                              \
    pk_.w = pk2(r_[6], r_[7]);                                              \
    *(uint4*)&s_col[(k) & 3][PX][goct * 8] = pk_;                           \
  } while (0)

#define GATHER(k, G)                                                        \
  do {                                                                      \
    GATHER1(k, &(G)[0], gpx0);                                              \
    GATHER1(k, &(G)[4], gpx1);                                              \
  } while (0)

#define PACKC(k, G)                                                         \
  do {                                                                      \
    PACK1(k, &(G)[0], gpx0);                                                \
    PACK1(k, &(G)[4], gpx1);                                                \
  } while (0)

// Fragment-stream weights: chunk k's A-tile for wave wv is 4 contiguous
// 1 KB wave-loads, prefetched ONE GROUP AHEAD into the afA/afB ping-pong.
#define LOADAF(k, AF)                                                       \
  do {                                                                      \
    const short8* wp_ = (const short8*)(P.wt) +                             \
                        ((size_t)((k) * 16 + wv * 4) << 6) + lane;          \
    _Pragma("unroll") for (int i_ = 0; i_ < 4; i_++) AF[i_] = wp_[i_ * 64]; \
  } while (0)

#define MFMA32(AF, CUR)                                                     \
  do {                                                                      \
    short8 bfr_[8];                                                         \
    _Pragma("unroll") for (int j_ = 0; j_ < 8; j_++)                        \
      bfr_[j_] = *(const short8*)&s_col[CUR][j_ * 16 + ln][quad * 8];       \
    _Pragma("unroll") for (int i_ = 0; i_ < 4; i_++)                        \
      _Pragma("unroll") for (int j_ = 0; j_ < 8; j_++)                      \
        acc[i_][j_] = __builtin_amdgcn_mfma_f32_16x16x32_bf16(              \
            AF[i_], bfr_[j_], acc[i_][j_], 0, 0, 0);                        \
  } while (0)

#define PHASE_BAR()                                                         \
  do {                                                                      \
    asm volatile("s_waitcnt lgkmcnt(0)" ::: "memory");                      \
    __builtin_amdgcn_s_barrier();                                           \
    __builtin_amdgcn_sched_barrier(0);                                      \
  } while (0)

__global__ __launch_bounds__(256, 2) void mdconv_kernel(MdBatch B) {
  __shared__ float4 s_cw[9][128];
  __shared__ int s_yy[9][128];  // packed y0*Wi | (y1*Wi)<<16
  __shared__ int s_xx[9][128];
  __shared__ unsigned short s_col[4][128][40];
  __shared__ float s_prof[128];

  int bx = blockIdx.x;
  int pidx = 0;
#pragma unroll
  for (int i = 1; i < 7; i++) pidx += (bx >= B.off[i]) ? 1 : 0;
  MdP P = B.p[pidx];
  int local = bx - B.off[pidx];
  // XCD banding: consecutive bx round-robin XCDs; give each XCD a
  // contiguous band of tiles for L2 locality.
  int ntile = 1 << P.ltile;
  int nslots = (NB << P.ltile) >> 3;
  int flat = (local & 7) * nslots + (local >> 3);
  int b = flat >> P.ltile;
  int pxt = flat & (ntile - 1);
  int Po = P.Wo << P.lWo;
  const unsigned short* xTb = P.xT + (size_t)b * P.Hi * P.Wi * CIN;

  int t = threadIdx.x;
  // resize weight profile (high path only; block-uniform branch)
  if (P.wsum) {
    if (t < P.Wo) s_prof[t] = 0.f;
    __syncthreads();
    if (t < P.Hro) {
      float r = (float)(P.Wo - 1) / (float)(P.Hro - 1);
      float sy = (float)t * r;
      int yl = (int)floorf(sy);
      float fy = sy - (float)yl;
      int yh = min(yl + 1, P.Wo - 1);
      atomicAdd(&s_prof[yl], 1.f - fy);
      atomicAdd(&s_prof[yh], fy);
    }
  }
  // Phase 0: sampling metadata for 9 taps x 128 px
  for (int e = t; e < 1152; e += 256) {
    int k = e >> 7, px = e & 127;
    int p = pxt * 128 + px;
    int i = p >> P.lWo, j = p & (P.Wo - 1);
    int pc = (i * P.omStep) * P.omW + j * P.omStep;
    const float* omb = P.om + (size_t)b * 27 * P.omP;
    float offy = omb[(size_t)(2 * k) * P.omP + pc];
    float offx = omb[(size_t)(2 * k + 1) * P.omP + pc];
    float m = omb[(size_t)(18 + k) * P.omP + pc];
    float py = (float)(i * P.stride) - 1.0f + (float)(k / 3) + offy;
    float pxf = (float)(j * P.stride) - 1.0f + (float)(k % 3) + offx;
    float y0f = floorf(py), x0f = floorf(pxf);
    float wy = py - y0f, wx = pxf - x0f;
    int y0 = (int)y0f, x0 = (int)x0f;
    int y1 = y0 + 1, x1 = x0 + 1;
    float vy0 = (y0 >= 0 && y0 < P.Hi) ? 1.f : 0.f;
    float vy1 = (y1 >= 0 && y1 < P.Hi) ? 1.f : 0.f;
    float vx0 = (x0 >= 0 && x0 < P.Wi) ? 1.f : 0.f;
    float vx1 = (x1 >= 0 && x1 < P.Wi) ? 1.f : 0.f;
    float4 cw;
    cw.x = (1.f - wy) * (1.f - wx) * m * vy0 * vx0;
    cw.y = (1.f - wy) * wx * m * vy0 * vx1;
    cw.z = wy * (1.f - wx) * m * vy1 * vx0;
    cw.w = wy * wx * m * vy1 * vx1;
    s_cw[k][px] = cw;
    int y0c = min(max(y0, 0), P.Hi - 1), y1c = min(max(y1, 0), P.Hi - 1);
    int x0c = min(max(x0, 0), P.Wi - 1), x1c = min(max(x1, 0), P.Wi - 1);
    s_yy[k][px] = (y0c * P.Wi) | ((y1c * P.Wi) << 16);
    s_xx[k][px] = x0c | (x1c << 16);
  }
  __syncthreads();

  floatx4 acc[4][8];
#pragma unroll
  for (int i = 0; i < 4; i++)
#pragma unroll
    for (int j = 0; j < 8; j++) acc[i][j] = (floatx4){0.f, 0.f, 0.f, 0.f};

  int lane = t & 63, wv = t >> 6;
  int quad = lane >> 4, ln = lane & 15;
  int wOc = wv * 64;
  int gpx0 = t >> 2, gpx1 = (t >> 2) + 64;  // two px items per thread
  int goct = t & 3;

  uint4 gA[8], gB[8];
  short8 afA[4], afB[4];

  // prologue: chunks 0,1 staged in s_col[0],[1]; gathers 2,3 and A-frags
  // 0,1 in flight.
  GATHER(0, gA);
  GATHER(1, gB);
  PACKC(0, gA);
  PACKC(1, gB);
  GATHER(2, gA);
  GATHER(3, gB);
  LOADAF(0, afA);
  LOADAF(1, afB);
  PHASE_BAR();

  // 36 groups; per group: 2 chunks consumed, 2 packed, 2 gathered,
  // 2 A-frag prefetches, ONE barrier. s_col ring of 4; group reads
  // {c0,c0+1}&3 and writes {c0+2,c0+3}&3 (disjoint).
  for (int c0 = 0; c0 < 72; c0 += 2) {
    MFMA32(afA, c0 & 3);
    if (c0 + 2 < 72) {
      LOADAF(c0 + 2, afA);
      PACKC(c0 + 2, gA);
    }
    if (c0 + 4 < 72) GATHER(c0 + 4, gA);
    MFMA32(afB, (c0 + 1) & 3);
    if (c0 + 3 < 72) {
      LOADAF(c0 + 3, afB);
      PACKC(c0 + 3, gB);
    }
    if (c0 + 5 < 72) GATHER(c0 + 5, gB);
    PHASE_BAR();
  }

  // epilogue: store C (col=lane&15 -> px, row=(lane>>4)*4+reg -> oc)
#pragma unroll
  for (int i = 0; i < 4; i++) {
    int ocB = wOc + i * 16 + quad * 4;
#pragma unroll
    for (int j = 0; j < 8; j++) {
      int px = pxt * 128 + j * 16 + ln;
#pragma unroll
      for (int r = 0; r < 4; r++)
        P.outf[((size_t)b * COUT + ocB + r) * Po + px] = acc[i][j][r];
    }
  }

  // fused stats: per-oc sum / sumsq (+ resize-weighted sum for high path)
  float pw[8];
  if (P.wsum) {
#pragma unroll
    for (int j = 0; j < 8; j++) {
      int px = pxt * 128 + j * 16 + ln;
      pw[j] = s_prof[px >> P.lWo] * s_prof[px & (P.Wo - 1)];
    }
  }
#pragma unroll
  for (int i = 0; i < 4; i++) {
    int ocB = wOc + i * 16 + quad * 4;
#pragma unroll
    for (int r = 0; r < 4; r++) {
      float s1 = 0.f, s2 = 0.f, sw = 0.f;
#pragma unroll
      for (int j = 0; j < 8; j++) {
        float v = acc[i][j][r];
        s1 += v;
        s2 += v * v;
        if (P.wsum) sw += v * pw[j];
      }
#pragma unroll
      for (int m = 1; m < 16; m <<= 1) {
        s1 += __shfl_xor(s1, m, 64);
        s2 += __shfl_xor(s2, m, 64);
        if (P.wsum) sw += __shfl_xor(sw, m, 64);
      }
      if (ln == 0) {
        atomicAdd(&P.sum[b * COUT + ocB + r], s1);
        atomicAdd(&P.sumsq[b * COUT + ocB + r], s2);
        if (P.wsum) atomicAdd(&P.wsum[b * COUT + ocB + r], sw);
      }
    }
  }
}

// ---------------------------------------------------------------------------
// All per-level scalar prep (GN affines, attention scalars, DyReLU MLP).
// One block per level (grid = 3).
// ---------------------------------------------------------------------------
struct PrepL {
  const float* st;  // 3584 floats: sumM,sqM,sumL,sqL,sumH,sqH,wsum
  float *Am, *Bm, *Al, *Bl, *Ah, *Bh, *svec, *coef;
  float invP, invPh, invn;
  int hasLow, hasHigh;
};
struct PrepB { PrepL L[3]; };

__global__ __launch_bounds__(256) void prep_all_kernel(
    PrepB PB, const float* __restrict__ g_mid, const float* __restrict__ be_mid,
    const float* __restrict__ g_low, const float* __restrict__ be_low,
    const float* __restrict__ g_high, const float* __restrict__ be_high,
    const float* __restrict__ w_sa, const float* __restrict__ b_sa,
    const float* __restrict__ w1, const float* __restrict__ b1,
    const float* __restrict__ w2, const float* __restrict__ b2) {
  __shared__ float s_m[3][NB][GN_GROUPS], s_iv[3][NB][GN_GROUPS];
  __shared__ float s_mean[3][NB][COUT];
  __shared__ float s_s[3][NB];
  __shared__ float s_nm[NB][COUT];
  __shared__ float s_h[NB][64];
  PrepL L = PB.L[blockIdx.x];
  const float* sumM = L.st;
  const float* sqM = L.st + 512;
  const float* sumL = L.st + 1024;
  const float* sqL = L.st + 1536;
  const float* sumH = L.st + 2048;
  const float* sqH = L.st + 2560;
  const float* swsum = L.st + 3072;
  int hasLow = L.hasLow, hasHigh = L.hasHigh;
  float invP = L.invP, invPh = L.invPh, invn = L.invn;
  int tid = threadIdx.x;

  if (tid < 96) {
    int path = tid / 32, b = (tid >> 4) & 1, g = tid & 15;
    int active = (path == 0) || (path == 1 && hasLow) || (path == 2 && hasHigh);
    if (active) {
      const float* su = path == 0 ? sumM : (path == 1 ? sumL : sumH);
      const float* sq = path == 0 ? sqM : (path == 1 ? sqL : sqH);
      float invN = ((path == 2) ? invPh : invP) * (1.f / 16.f);
      float s = 0.f, q = 0.f;
      for (int c = g * 16; c < g * 16 + 16; c++) {
        s += su[b * COUT + c];
        q += sq[b * COUT + c];
      }
      float m = s * invN;
      float v = q * invN - m * m;
      s_m[path][b][g] = m;
      s_iv[path][b][g] = rsqrtf(v + 1e-5f);
    }
  }
  __syncthreads();
  for (int idx = tid; idx < 3 * NB * COUT; idx += 256) {
    int path = idx / (NB * COUT);
    int r = idx % (NB * COUT);
    int b = r / COUT, c = r % COUT, g = c >> 4;
    int active = (path == 0) || (path == 1 && hasLow) || (path == 2 && hasHigh);
    if (active) {
      const float* ga = path == 0 ? g_mid : (path == 1 ? g_low : g_high);
      const float* be = path == 0 ? be_mid : (path == 1 ? be_low : be_high);
      float a = ga[c] * s_iv[path][b][g];
      float bb = be[c] - s_m[path][b][g] * a;
      float mean;
      if (path == 2)
        mean = a * (swsum[r] * invP) + bb;
      else {
        const float* su = path == 0 ? sumM : sumL;
        mean = a * (su[r] * invP) + bb;
      }
      float* Ad = path == 0 ? L.Am : (path == 1 ? L.Al : L.Ah);
      float* Bd = path == 0 ? L.Bm : (path == 1 ? L.Bl : L.Bh);
      Ad[r] = a;
      Bd[r] = bb;
      s_mean[path][b][c] = mean;
    }
  }
  __syncthreads();
  if (tid < 6) {
    int path = tid >> 1, b = tid & 1;
    int active = (path == 0) || (path == 1 && hasLow) || (path == 2 && hasHigh);
    float s = 0.f;
    if (active) {
      float t = 0.f;
      for (int c = 0; c < COUT; c++) t += s_mean[path][b][c] * w_sa[c];
      t += b_sa[0];
      t = fmaxf(t, 0.0f);
      s = fminf(fmaxf(t + 3.f, 0.f), 6.f) * (1.f / 6.f);
      L.svec[path * NB + b] = s;
    }
    s_s[path][b] = s;
  }
  __syncthreads();
  for (int idx = tid; idx < NB * COUT; idx += 256) {
    int b = idx / COUT, c = idx % COUT;
    float v = s_s[0][b] * s_mean[0][b][c];
    if (hasLow) v += s_s[1][b] * s_mean[1][b][c];
    if (hasHigh) v += s_s[2][b] * s_mean[2][b][c];
    s_nm[b][c] = v * invn;
  }
  __syncthreads();
  if (tid < NB * 64) {
    int b = tid / 64, j = tid % 64;
    float t = b1[j];
    for (int c = 0; c < COUT; c++) t += s_nm[b][c] * w1[j * COUT + c];
    s_h[b][j] = fmaxf(t, 0.f);
  }
  __syncthreads();
  for (int idx = tid; idx < NB * 1024; idx += 256) {
    int b = idx / 1024, i = idx % 1024;
    float t = b2[i];
    for (int j = 0; j < 64; j++) t += s_h[b][j] * w2[i * 64 + j];
    L.coef[idx] = fminf(fmaxf(t + 3.f, 0.f), 6.f) * (1.f / 6.f) - 0.5f;
  }
}

// ---------------------------------------------------------------------------
// Fused epilogue: GN-affine+scale of mid (+low) (+bilinear-resized high),
// then DyReLU. All three levels in one launch; float4 / 4 px per thread.
// ---------------------------------------------------------------------------
struct ApL {
  const float* featM; const float* featL; const float* featH;
  const float* Am; const float* Bm; const float* Al; const float* Bl;
  const float* Ah; const float* Bh; const float* svec; const float* coef;
  float* out;
  int lP, lHo, Hh, hasLow, hasHigh;
  float invn;
};
struct ApB { ApL L[3]; int off[4]; };

__global__ __launch_bounds__(256) void fused_apply_kernel(ApB A) {
  int bx = blockIdx.x;
  int li = (bx >= A.off[1] ? 1 : 0) + (bx >= A.off[2] ? 1 : 0);
  ApL L = A.L[li];
  int idx = ((bx - A.off[li]) * 256 + threadIdx.x) * 4;
  int bc = idx >> L.lP;
  int p0 = idx & ((1 << L.lP) - 1);
  int b = bc >> 8, c = bc & 255;
  float am = L.Am[bc], bm = L.Bm[bc], sm = L.svec[b];
  float4 fm = *(const float4*)&L.featM[idx];
  float v0 = (fm.x * am + bm) * sm;
  float v1 = (fm.y * am + bm) * sm;
  float v2 = (fm.z * am + bm) * sm;
  float v3 = (fm.w * am + bm) * sm;
  if (L.hasLow) {
    float al = L.Al[bc], bl = L.Bl[bc], sl = L.svec[2 + b];
    float4 fl = *(const float4*)&L.featL[idx];
    v0 += (fl.x * al + bl) * sl;
    v1 += (fl.y * al + bl) * sl;
    v2 += (fl.z * al + bl) * sl;
    v3 += (fl.w * al + bl) * sl;
  }
  if (L.hasHigh) {
    int Ho = 1 << L.lHo;
    int Y = p0 >> L.lHo, X0 = p0 & (Ho - 1);  // 4 px share one row
    float r = (float)(L.Hh - 1) / (float)(Ho - 1);
    float sy = (float)Y * r;
    int yl = (int)floorf(sy);
    int yh = min(yl + 1, L.Hh - 1);
    float wy = sy - (float)yl;
    float ah = L.Ah[bc], bh = L.Bh[bc], sh = L.svec[4 + b];
    const float* fp = L.featH + (size_t)bc * L.Hh * L.Hh;
    const float* fpl = fp + yl * L.Hh;
    const float* fph = fp + yh * L.Hh;
    float hv[4];
#pragma unroll
    for (int j = 0; j < 4; j++) {
      float sx = (float)(X0 + j) * r;
      int xl = (int)floorf(sx);
      int xh = min(xl + 1, L.Hh - 1);
      float wx = sx - (float)xl;
      float t0 = fpl[xl] * (1.f - wx) + fpl[xh] * wx;
      float t1 = fph[xl] * (1.f - wx) + fph[xh] * wx;
      hv[j] = ((t0 * (1.f - wy) + t1 * wy) * ah + bh) * sh;
    }
    v0 += hv[0]; v1 += hv[1]; v2 += hv[2]; v3 += hv[3];
  }
  float a1 = L.coef[b * 1024 + c] * 2.f + 1.f;
  float b1v = L.coef[b * 1024 + 256 + c];
  float a2 = L.coef[b * 1024 + 512 + c] * 2.f;
  float b2v = L.coef[b * 1024 + 768 + c];
  float4 o;
  float x0 = v0 * L.invn, x1 = v1 * L.invn, x2 = v2 * L.invn, x3 = v3 * L.invn;
  o.x = fmaxf(x0 * a1 + b1v, x0 * a2 + b2v);
  o.y = fmaxf(x1 * a1 + b1v, x1 * a2 + b2v);
  o.z = fmaxf(x2 * a1 + b1v, x2 * a2 + b2v);
  o.w = fmaxf(x3 * a1 + b1v, x3 * a2 + b2v);
  *(float4*)&L.out[idx] = o;
}

// ---------------------------------------------------------------------------
extern "C" void kernel_launch(void* const* d_in, const int* in_sizes, int n_in,
                              void* d_out, int out_size, void* d_ws,
                              size_t ws_size, hipStream_t stream) {
  (void)in_sizes; (void)n_in; (void)out_size; (void)ws_size;
  const float* x[3] = {(const float*)d_in[0], (const float*)d_in[1],
                       (const float*)d_in[2]};
  const float* w_off = (const float*)d_in[3];
  const float* b_off = (const float*)d_in[4];
  const float* w_mid = (const float*)d_in[5];
  const float* g_mid = (const float*)d_in[6];
  const float* be_mid = (const float*)d_in[7];
  const float* w_low = (const float*)d_in[8];
  const float* g_low = (const float*)d_in[9];
  const float* be_low = (const float*)d_in[10];
  const float* w_high = (const float*)d_in[11];
  const float* g_high = (const float*)d_in[12];
  const float* be_high = (const float*)d_in[13];
  const float* w_sa = (const float*)d_in[14];
  const float* b_sa = (const float*)d_in[15];
  const float* w_dy1 = (const float*)d_in[16];
  const float* b_dy1 = (const float*)d_in[17];
  const float* w_dy2 = (const float*)d_in[18];
  const float* b_dy2 = (const float*)d_in[19];

  float* out = (float*)d_out;
  char* wsb = (char*)d_ws;
  size_t o = 0;
  unsigned short* xT0 = (unsigned short*)(wsb + o); o += 16777216;
  unsigned short* xT1 = (unsigned short*)(wsb + o); o += 4194304;
  unsigned short* xT2 = (unsigned short*)(wsb + o); o += 1048576;
  unsigned short* wtm = (unsigned short*)(wsb + o); o += 1179648;
  unsigned short* wtl = (unsigned short*)(wsb + o); o += 1179648;
  unsigned short* wth = (unsigned short*)(wsb + o); o += 1179648;
  unsigned short* wo  = (unsigned short*)(wsb + o); o += 294912;
  float* om0 = (float*)(wsb + o); o += 3538944;
  float* om1 = (float*)(wsb + o); o += 884736;
  float* om2 = (float*)(wsb + o); o += 221184;
  float* arena = (float*)(wsb + o); o += 65011712;  // all levels' feats
  float* stats = (float*)(wsb + o); o += 43072;     // 3x3584 floats
  float* Am = (float*)(wsb + o); o += 6144;         // 3 x 512 floats each
  float* Bm = (float*)(wsb + o); o += 6144;
  float* Al = (float*)(wsb + o); o += 6144;
  float* Bl = (float*)(wsb + o); o += 6144;
  float* Ah = (float*)(wsb + o); o += 6144;
  float* Bh = (float*)(wsb + o); o += 6144;
  float* svec = (float*)(wsb + o); o += 192;        // 3 x 16 floats
  float* dycoef = (float*)(wsb + o); o += 24576;    // 3 x 2048 floats

  // per-level feature buffers (floats), all live simultaneously
  float* featM0 = arena;                  // 2*256*16384
  float* featH0 = arena + 8388608;        // 2*256*4096
  float* featM1 = arena + 10485760;       // 2*256*4096
  float* featL1 = arena + 12582912;       // 2*256*4096
  float* featH1 = arena + 14680064;       // 2*256*1024
  float* featM2 = arena + 15204352;       // 2*256*1024
  float* featL2 = arena + 15728640;       // 2*256*1024

  // x_lo scratch aliases the arena (consumed by conv_offset before any
  // mdconv writes feats).
  unsigned short* xLo0 = (unsigned short*)arena;
  unsigned short* xLo1 = xLo0 + 8388608;
  unsigned short* xLo2 = xLo1 + 2097152;

  // One setup launch: transposes + weight repacks + stats zeroing.
  SetB sb = {x[0], x[1], x[2], w_mid, w_low, w_high, w_off,
             xT0, xT1, xT2, xLo0, xLo1, xLo2, wtm, wtl, wth, wo, stats};
  setup_kernel<<<10219, 256, 0, stream>>>(sb);

  // Batched offset conv over all 3 levels.
  CoB cob;
  cob.L[0] = {xT0, xLo0, om0, 128, 128, 64, 6, 1, 16384};
  cob.L[1] = {xT1, xLo1, om1, 64, 64, 64, 6, 1, 4096};
  cob.L[2] = {xT2, xLo2, om2, 32, 32, 32, 5, 2, 1024};
  cob.off[0] = 0; cob.off[1] = 512; cob.off[2] = 640; cob.off[3] = 672;
  conv_offset_kernel<<<672, 256, 0, stream>>>(cob, wo, b_off);

  // All 7 mdconv paths (3 levels) in one launch; 128-px tiles, 496 blocks.
  float* S0 = stats;
  float* S1 = stats + 3584;
  float* S2 = stats + 7168;
  MdBatch mb;
  mb.p[0] = {xT0, wtm, featM0, om0, S0, S0 + 512, nullptr,
             128, 128, 128, 7, 1, 1, 128, 16384, 7, 0};          // l0 mid 256
  mb.p[1] = {xT1, wth, featH0, om0, S0 + 2048, S0 + 2560, S0 + 3072,
             64, 64, 64, 6, 1, 2, 128, 16384, 5, 128};           // l0 high 64
  mb.p[2] = {xT1, wtm, featM1, om1, S1, S1 + 512, nullptr,
             64, 64, 64, 6, 1, 1, 64, 4096, 5, 0};               // l1 mid 64
  mb.p[3] = {xT0, wtl, featL1, om1, S1 + 1024, S1 + 1536, nullptr,
             128, 128, 64, 6, 2, 1, 64, 4096, 5, 0};             // l1 low 64
  mb.p[4] = {xT2, wth, featH1, om1, S1 + 2048, S1 + 2560, S1 + 3072,
             32, 32, 32, 5, 1, 2, 64, 4096, 3, 64};              // l1 high 16
  mb.p[5] = {xT2, wtm, featM2, om2, S2, S2 + 512, nullptr,
             32, 32, 32, 5, 1, 1, 32, 1024, 3, 0};               // l2 mid 16
  mb.p[6] = {xT1, wtl, featL2, om2, S2 + 1024, S2 + 1536, nullptr,
             64, 64, 32, 5, 2, 1, 32, 1024, 3, 0};               // l2 low 16
  mb.off[0] = 0;   mb.off[1] = 256; mb.off[2] = 320; mb.off[3] = 384;
  mb.off[4] = 448; mb.off[5] = 464; mb.off[6] = 480;
  mdconv_kernel<<<496, 256, 0, stream>>>(mb);

  // Per-level scalar prep: one block per level.
  PrepB pb;
  {
    const int Hs[3] = {128, 64, 32};
    const float nterm[3] = {2.f, 3.f, 2.f};
    for (int l = 0; l < 3; l++) {
      int H = Hs[l];
      int Pp = H * H;
      int Ph = (H / 2) * (H / 2);
      pb.L[l] = {stats + l * 3584, Am + l * 512, Bm + l * 512, Al + l * 512,
                 Bl + l * 512, Ah + l * 512, Bh + l * 512, svec + l * 16,
                 dycoef + l * 2048, 1.0f / (float)Pp, 1.0f / (float)Ph,
                 1.0f / nterm[l], l > 0 ? 1 : 0, l < 2 ? 1 : 0};
    }
  }
  prep_all_kernel<<<3, 256, 0, stream>>>(pb, g_mid, be_mid, g_low, be_low,
                                         g_high, be_high, w_sa, b_sa, w_dy1,
                                         b_dy1, w_dy2, b_dy2);

  // Fused epilogue, all levels in one launch; 4 px per thread.
  ApB ab;
  ab.L[0] = {featM0, featM0, featH0, Am, Bm, Al, Bl, Ah, Bh, svec, dycoef,
             out, 14, 7, 64, 0, 1, 0.5f};
  ab.L[1] = {featM1, featL1, featH1, Am + 512, Bm + 512, Al + 512, Bl + 512,
             Ah + 512, Bh + 512, svec + 16, dycoef + 2048, out + 8388608,
             12, 6, 32, 1, 1, 1.0f / 3.0f};
  ab.L[2] = {featM2, featL2, featM2, Am + 1024, Bm + 1024, Al + 1024,
             Bl + 1024, Ah + 1024, Bh + 1024, svec + 32, dycoef + 4096,
             out + 10485760, 10, 5, 16, 1, 0, 0.5f};
  ab.off[0] = 0; ab.off[1] = 8192; ab.off[2] = 10240; ab.off[3] = 10752;
  fused_apply_kernel<<<10752, 256, 0, stream>>>(ab);
}

// Round 12
// 400.602 us; speedup vs baseline: 1.1154x; 1.1154x over previous
//
#include <hip/hip_runtime.h>
#include <hip/hip_bf16.h>
#include <math.h>

#define CIN 256
#define COUT 256
#define NB 2
#define GN_GROUPS 16

typedef __attribute__((ext_vector_type(8))) short short8;
typedef __attribute__((ext_vector_type(4))) float floatx4;

__device__ __forceinline__ float b2f(unsigned short u) {
  union { unsigned int i; float f; } v;
  v.i = ((unsigned int)u) << 16;
  return v.f;
}
__device__ __forceinline__ unsigned short f2b(float f) {
  union { float f; unsigned int i; } v;
  v.f = f;
  unsigned int r = (v.i + 0x7FFFu + ((v.i >> 16) & 1u)) >> 16;
  return (unsigned short)r;
}
__device__ __forceinline__ float lo2f(unsigned int u) {
  union { unsigned int i; float f; } v;
  v.i = u << 16;
  return v.f;
}
__device__ __forceinline__ float hi2f(unsigned int u) {
  union { unsigned int i; float f; } v;
  v.i = u & 0xffff0000u;
  return v.f;
}
__device__ __forceinline__ unsigned int pk2(float a, float b) {
  union { __hip_bfloat162 h; unsigned int u; } v;
  v.h = __float22bfloat162_rn(float2{a, b});
  return v.u;
}

// ---------------------------------------------------------------------------
// Setup: NCHW->NHWC split-bf16 transpose (all levels) + mdconv weight repack
// (fragment-stream) + offset-conv weight repack + stats zeroing.
// One launch, block-range dispatch. Grid = 2688 + 6912 + 576 + 43 = 10219.
// ---------------------------------------------------------------------------
struct SetB {
  const float *x0, *x1, *x2, *wm, *wl, *wh, *wof;
  unsigned short *t0, *t1, *t2, *l0, *l1, *l2;
  unsigned short *wtm, *wtl, *wth, *wo;
  float* stats;  // 10752 floats
};

__global__ __launch_bounds__(256) void setup_kernel(SetB A) {
  __shared__ float tile[64][65];
  int bx = blockIdx.x, t = threadIdx.x;
  if (bx < 2688) {
    // ---- transpose: decode original dim3(336,4,NB) ----
    int xg = bx % 336;
    int rem = bx / 336;
    int yg = rem & 3, zg = rem >> 2;
    int li = (xg >= 256 ? 1 : 0) + (xg >= 320 ? 1 : 0);
    int local = xg - (li == 0 ? 0 : (li == 1 ? 256 : 320));
    const float* x = li == 0 ? A.x0 : (li == 1 ? A.x1 : A.x2);
    unsigned short* xT = li == 0 ? A.t0 : (li == 1 ? A.t1 : A.t2);
    unsigned short* xLo = li == 0 ? A.l0 : (li == 1 ? A.l1 : A.l2);
    int P = li == 0 ? 16384 : (li == 1 ? 4096 : 1024);
    int pBase = local * 64, cBase = yg * 64, b = zg;
    int pl = t & 63, ch = t >> 6;
    const float* xb = x + ((size_t)b * CIN + cBase) * P + pBase;
#pragma unroll
    for (int e = 0; e < 16; e++) {
      int c = ch * 16 + e;
      tile[c][pl] = xb[(size_t)c * P + pl];
    }
    __syncthreads();
    size_t obase = ((size_t)b * P + pBase) * CIN + cBase;
    int cl = t & 63, pr = t >> 6;
#pragma unroll
    for (int e = 0; e < 16; e++) {
      int p = pr * 16 + e;
      float v = tile[cl][p];
      unsigned short h = f2b(v);
      xT[obase + (size_t)p * CIN + cl] = h;
      xLo[obase + (size_t)p * CIN + cl] = f2b(v - b2f(h));
    }
  } else if (bx < 9600) {
    // ---- mdconv weight repack: fragment-stream wtf[kc][wv][i][lane][8] ----
    int lb = bx - 2688;
    int sel = (lb >= 2304 ? 1 : 0) + (lb >= 4608 ? 1 : 0);
    const float* w = sel == 0 ? A.wm : (sel == 1 ? A.wl : A.wh);
    unsigned short* wt = sel == 0 ? A.wtm : (sel == 1 ? A.wtl : A.wth);
    int idx = (lb - sel * 2304) * 256 + t;  // 589824 = 72*8192
    int e = idx & 7;
    int lane = (idx >> 3) & 63;
    int i = (idx >> 9) & 3;
    int wv = (idx >> 11) & 3;
    int kc = idx >> 13;  // 0..71
    int oc = wv * 64 + i * 16 + (lane & 15);
    int c = (kc & 7) * 32 + (lane >> 4) * 8 + e;
    int tap = kc >> 3;
    wt[idx] = f2b(w[(size_t)oc * 2304 + c * 9 + tap]);
  } else if (bx < 10176) {
    // ---- offset-conv weight repack: wo[sel][tap][cb][oc32][ch32] ----
    int idx = (bx - 9600) * 256 + t;  // 2*73728
    int sel = idx / 73728;
    int r = idx % 73728;
    int k = r / 8192;
    int r2 = r % 8192;
    int cbk = r2 / 1024;
    int oc = (r2 / 32) % 32;
    int ch = r2 % 32;
    int c = cbk * 32 + ch;
    float val = (oc < 27) ? A.wof[(size_t)oc * 2304 + c * 9 + k] : 0.0f;
    float hi = b2f(f2b(val));
    A.wo[idx] = sel ? f2b(val - hi) : f2b(val);
  } else {
    // ---- zero stats ----
    int idx = (bx - 10176) * 256 + t;
    if (idx < 10752) A.stats[idx] = 0.f;
  }
}

// ---------------------------------------------------------------------------
// Offset conv: halo-staged LDS + MFMA, split-bf16, batched over levels.
// ---------------------------------------------------------------------------
struct CoL {
  const unsigned short* xhi;
  const unsigned short* xlo;
  float* om;
  int H, W, Cs, cshift, Rs, P;
};
struct CoB { CoL L[3]; int off[4]; };

__global__ __launch_bounds__(256) void conv_offset_kernel(
    CoB B, const unsigned short* __restrict__ wo,
    const float* __restrict__ bias) {
  __shared__ unsigned short s_hi[204 * 40];
  __shared__ unsigned short s_lo[204 * 40];
  int bx = blockIdx.x;
  int li = (bx >= B.off[1] ? 1 : 0) + (bx >= B.off[2] ? 1 : 0);
  CoL L = B.L[li];
  int local = bx - B.off[li];
  int tpb = L.P / 64;
  int b = local / tpb, pxt = local % tpb;
  int t = threadIdx.x;
  int pbase = pxt * 64;
  int r0 = pbase / L.W;
  int c0 = pbase % L.W;
  int Ct = L.Cs + 2;
  int Npos = Ct * (L.Rs + 2);
  const unsigned short* xhib = L.xhi + (size_t)b * L.P * CIN;
  const unsigned short* xlob = L.xlo + (size_t)b * L.P * CIN;

  int lane = t & 63, wv = t >> 6, quad = lane >> 4, ln = lane & 15;
  int pl = wv * 16 + ln;
  int pi_ = pl >> L.cshift;
  int pj_ = pl & (L.Cs - 1);

  floatx4 acc0 = {0.f, 0.f, 0.f, 0.f}, acc1 = {0.f, 0.f, 0.f, 0.f};

  for (int cb = 0; cb < 8; cb++) {
    __syncthreads();
    for (int e = t; e < Npos * 4; e += 256) {
      int pos = e >> 2, oct = e & 3;
      int r = pos / Ct, c = pos % Ct;
      int gy = r0 - 1 + r, gx = c0 - 1 + c;
      uint4 vhi = {0, 0, 0, 0}, vlo = {0, 0, 0, 0};
      if (gy >= 0 && gy < L.H && gx >= 0 && gx < L.W) {
        size_t off = ((size_t)(gy * L.W + gx)) * CIN + cb * 32 + oct * 8;
        vhi = *(const uint4*)(xhib + off);
        vlo = *(const uint4*)(xlob + off);
      }
      *(uint4*)&s_hi[pos * 40 + oct * 8] = vhi;
      *(uint4*)&s_lo[pos * 40 + oct * 8] = vlo;
    }
    __syncthreads();
#pragma unroll
    for (int tap = 0; tap < 9; tap++) {
      int dy = tap / 3 - 1, dx = tap % 3 - 1;
      const unsigned short* wb0 = wo + (size_t)((0 * 9 + tap) * 8 + cb) * 1024;
      const unsigned short* wb1 = wo + (size_t)((1 * 9 + tap) * 8 + cb) * 1024;
      short8 whi0 = *(const short8*)(wb0 + ln * 32 + quad * 8);
      short8 whi1 = *(const short8*)(wb0 + (16 + ln) * 32 + quad * 8);
      short8 wlo0 = *(const short8*)(wb1 + ln * 32 + quad * 8);
      short8 wlo1 = *(const short8*)(wb1 + (16 + ln) * 32 + quad * 8);
      int pos = (pi_ + dy + 1) * Ct + (pj_ + dx + 1);
      short8 bhi = *(const short8*)&s_hi[pos * 40 + quad * 8];
      short8 blo = *(const short8*)&s_lo[pos * 40 + quad * 8];
      acc0 = __builtin_amdgcn_mfma_f32_16x16x32_bf16(whi0, bhi, acc0, 0, 0, 0);
      acc1 = __builtin_amdgcn_mfma_f32_16x16x32_bf16(whi1, bhi, acc1, 0, 0, 0);
      acc0 = __builtin_amdgcn_mfma_f32_16x16x32_bf16(wlo0, bhi, acc0, 0, 0, 0);
      acc1 = __builtin_amdgcn_mfma_f32_16x16x32_bf16(wlo1, bhi, acc1, 0, 0, 0);
      acc0 = __builtin_amdgcn_mfma_f32_16x16x32_bf16(whi0, blo, acc0, 0, 0, 0);
      acc1 = __builtin_amdgcn_mfma_f32_16x16x32_bf16(whi1, blo, acc1, 0, 0, 0);
    }
  }

  int px = pbase + pl;
#pragma unroll
  for (int i2 = 0; i2 < 2; i2++) {
#pragma unroll
    for (int r = 0; r < 4; r++) {
      int oc = i2 * 16 + quad * 4 + r;
      if (oc < 27) {
        float val = (i2 == 0 ? acc0[r] : acc1[r]) + bias[oc];
        if (oc >= 18) val = 1.f / (1.f + __expf(-val));
        L.om[((size_t)b * 27 + oc) * L.P + px] = val;
      }
    }
  }
}

// ---------------------------------------------------------------------------
// Modulated deformable conv v12 (PROVEN BEST: 151-152us; R8/R10).
// 64-px tiles, (256,3), 2 chunks per barrier group, 4-deep s_col ring,
// A-frag double-buffer, fragment-stream weights, raw s_barrier.
// Geometry space is CLOSED (R3/R9/R11): the gfx950 allocator snaps arch
// regs to {64,128,256} quanta; 32-px@16-wave and 128-px@8-wave both spill
// (WRITE_SIZE 72 -> 90/237 MB). 64-px@12-wave (84 arch + 64 acc) is the
// only spill-free point. The 992-block / 768-slot two-round quantization
// is structural at this tile size.
// ---------------------------------------------------------------------------
struct MdP {
  const unsigned short* xT;
  const unsigned short* wt;
  float* outf;
  const float* om;
  float* sum;
  float* sumsq;
  float* wsum;  // non-null for high path
  int Hi, Wi, Wo, lWo, stride, omStep, omW, omP, ltile, Hro;
};
struct MdBatch { MdP p[7]; int off[7]; };

#define GATHER(k, G)                                                        \
  do {                                                                      \
    int tap_ = (k) >> 3, cbk_ = (k) & 7;                                    \
    int yy_ = s_yy[tap_][gpx], xx_ = s_xx[tap_][gpx];                       \
    int y0_ = yy_ & 0xffff, y1_ = (yy_ >> 16) & 0xffff;                     \
    int x0_ = xx_ & 0xffff, x1_ = (xx_ >> 16) & 0xffff;                     \
    const unsigned short* gb_ = xTb + cbk_ * 32 + goct * 8;                 \
    G[0] = *(const uint4*)(gb_ + (size_t)(y0_ + x0_) * CIN);                \
    G[1] = *(const uint4*)(gb_ + (size_t)(y0_ + x1_) * CIN);                \
    G[2] = *(const uint4*)(gb_ + (size_t)(y1_ + x0_) * CIN);                \
    G[3] = *(const uint4*)(gb_ + (size_t)(y1_ + x1_) * CIN);                \
  } while (0)

#define PACKC(k, G)                                                         \
  do {                                                                      \
    float4 cw_ = s_cw[(k) >> 3][gpx];                                       \
    float r_[8];                                                            \
    _Pragma("unroll") for (int j_ = 0; j_ < 4; j_++) {                      \
      unsigned int a_ = ((unsigned int*)&G[0])[j_];                         \
      unsigned int b2_ = ((unsigned int*)&G[1])[j_];                        \
      unsigned int c_ = ((unsigned int*)&G[2])[j_];                         \
      unsigned int d_ = ((unsigned int*)&G[3])[j_];                         \
      r_[2 * j_] = cw_.x * lo2f(a_) + cw_.y * lo2f(b2_) +                   \
                   cw_.z * lo2f(c_) + cw_.w * lo2f(d_);                     \
      r_[2 * j_ + 1] = cw_.x * hi2f(a_) + cw_.y * hi2f(b2_) +               \
                       cw_.z * hi2f(c_) + cw_.w * hi2f(d_);                 \
    }                                                                       \
    uint4 pk_;                                                              \
    pk_.x = pk2(r_[0], r_[1]);                                              \
    pk_.y = pk2(r_[2], r_[3]);                                              \
    pk_.z = pk2(r_[4], r_[5]);                                              \
    pk_.w = pk2(r_[6], r_[7]);                                              \
    *(uint4*)&s_col[(k) & 3][gpx][goct * 8] = pk_;                          \
  } while (0)

// Fragment-stream weights: chunk k's A-tile for wave wv is 4 contiguous
// 1 KB wave-loads, prefetched ONE GROUP AHEAD into the afA/afB ping-pong.
#define LOADAF(k, AF)                                                       \
  do {                                                                      \
    const short8* wp_ = (const short8*)(P.wt) +                             \
                        ((size_t)((k) * 16 + wv * 4) << 6) + lane;          \
    _Pragma("unroll") for (int i_ = 0; i_ < 4; i_++) AF[i_] = wp_[i_ * 64]; \
  } while (0)

#define MFMA16(AF, CUR)                                                     \
  do {                                                                      \
    short8 bfr_[4];                                                         \
    _Pragma("unroll") for (int j_ = 0; j_ < 4; j_++)                        \
      bfr_[j_] = *(const short8*)&s_col[CUR][j_ * 16 + ln][quad * 8];       \
    _Pragma("unroll") for (int i_ = 0; i_ < 4; i_++)                        \
      _Pragma("unroll") for (int j_ = 0; j_ < 4; j_++)                      \
        acc[i_][j_] = __builtin_amdgcn_mfma_f32_16x16x32_bf16(              \
            AF[i_], bfr_[j_], acc[i_][j_], 0, 0, 0);                        \
  } while (0)

#define PHASE_BAR()                                                         \
  do {                                                                      \
    asm volatile("s_waitcnt lgkmcnt(0)" ::: "memory");                      \
    __builtin_amdgcn_s_barrier();                                           \
    __builtin_amdgcn_sched_barrier(0);                                      \
  } while (0)

__global__ __launch_bounds__(256, 3) void mdconv_kernel(MdBatch B) {
  __shared__ float4 s_cw[9][64];
  __shared__ int s_yy[9][64];   // packed y0*Wi | (y1*Wi)<<16
  __shared__ int s_xx[9][64];
  __shared__ unsigned short s_col[4][64][40];
  __shared__ float s_prof[64];

  int bx = blockIdx.x;
  int pidx = 0;
#pragma unroll
  for (int i = 1; i < 7; i++) pidx += (bx >= B.off[i]) ? 1 : 0;
  MdP P = B.p[pidx];
  int local = bx - B.off[pidx];
  // XCD banding: consecutive bx round-robin XCDs; give each XCD a
  // contiguous band of tiles for L2 locality.
  int ntile = 1 << P.ltile;
  int nslots = (NB << P.ltile) >> 3;
  int flat = (local & 7) * nslots + (local >> 3);
  int b = flat >> P.ltile;
  int pxt = flat & (ntile - 1);
  int Po = P.Wo << P.lWo;
  const unsigned short* xTb = P.xT + (size_t)b * P.Hi * P.Wi * CIN;

  int t = threadIdx.x;
  // resize weight profile (high path only; block-uniform branch)
  if (P.wsum) {
    if (t < P.Wo) s_prof[t] = 0.f;
    __syncthreads();
    if (t < P.Hro) {
      float r = (float)(P.Wo - 1) / (float)(P.Hro - 1);
      float sy = (float)t * r;
      int yl = (int)floorf(sy);
      float fy = sy - (float)yl;
      int yh = min(yl + 1, P.Wo - 1);
      atomicAdd(&s_prof[yl], 1.f - fy);
      atomicAdd(&s_prof[yh], fy);
    }
  }
  // Phase 0: sampling metadata for 9 taps x 64 px
  for (int e = t; e < 576; e += 256) {
    int k = e / 64, px = e % 64;
    int p = pxt * 64 + px;
    int i = p >> P.lWo, j = p & (P.Wo - 1);
    int pc = (i * P.omStep) * P.omW + j * P.omStep;
    const float* omb = P.om + (size_t)b * 27 * P.omP;
    float offy = omb[(size_t)(2 * k) * P.omP + pc];
    float offx = omb[(size_t)(2 * k + 1) * P.omP + pc];
    float m = omb[(size_t)(18 + k) * P.omP + pc];
    float py = (float)(i * P.stride) - 1.0f + (float)(k / 3) + offy;
    float pxf = (float)(j * P.stride) - 1.0f + (float)(k % 3) + offx;
    float y0f = floorf(py), x0f = floorf(pxf);
    float wy = py - y0f, wx = pxf - x0f;
    int y0 = (int)y0f, x0 = (int)x0f;
    int y1 = y0 + 1, x1 = x0 + 1;
    float vy0 = (y0 >= 0 && y0 < P.Hi) ? 1.f : 0.f;
    float vy1 = (y1 >= 0 && y1 < P.Hi) ? 1.f : 0.f;
    float vx0 = (x0 >= 0 && x0 < P.Wi) ? 1.f : 0.f;
    float vx1 = (x1 >= 0 && x1 < P.Wi) ? 1.f : 0.f;
    float4 cw;
    cw.x = (1.f - wy) * (1.f - wx) * m * vy0 * vx0;
    cw.y = (1.f - wy) * wx * m * vy0 * vx1;
    cw.z = wy * (1.f - wx) * m * vy1 * vx0;
    cw.w = wy * wx * m * vy1 * vx1;
    s_cw[k][px] = cw;
    int y0c = min(max(y0, 0), P.Hi - 1), y1c = min(max(y1, 0), P.Hi - 1);
    int x0c = min(max(x0, 0), P.Wi - 1), x1c = min(max(x1, 0), P.Wi - 1);
    s_yy[k][px] = (y0c * P.Wi) | ((y1c * P.Wi) << 16);
    s_xx[k][px] = x0c | (x1c << 16);
  }
  __syncthreads();

  floatx4 acc[4][4];
#pragma unroll
  for (int i = 0; i < 4; i++)
#pragma unroll
    for (int j = 0; j < 4; j++) acc[i][j] = (floatx4){0.f, 0.f, 0.f, 0.f};

  int lane = t & 63, wv = t >> 6;
  int quad = lane >> 4, ln = lane & 15;
  int wOc = wv * 64;
  int gpx = t >> 2, goct = t & 3;  // gather item: (px, 8-ch octet)

  uint4 gA[4], gB[4];
  short8 afA[4], afB[4];

  // prologue: chunks 0,1 staged in s_col[0],[1]; gathers 2,3 and A-frags
  // 0,1 in flight.
  GATHER(0, gA);
  GATHER(1, gB);
  PACKC(0, gA);
  PACKC(1, gB);
  GATHER(2, gA);
  GATHER(3, gB);
  LOADAF(0, afA);
  LOADAF(1, afB);
  PHASE_BAR();

  // 36 groups; per group: 2 chunks consumed, 2 packed, 2 gathered,
  // 2 A-frag prefetches, ONE barrier. Buffers: s_col ring of 4; group g
  // reads {c0,c0+1}&3 and writes {c0+2,c0+3}&3 (disjoint).
  for (int c0 = 0; c0 < 72; c0 += 2) {
    MFMA16(afA, c0 & 3);
    if (c0 + 2 < 72) {
      LOADAF(c0 + 2, afA);
      PACKC(c0 + 2, gA);
    }
    if (c0 + 4 < 72) GATHER(c0 + 4, gA);
    MFMA16(afB, (c0 + 1) & 3);
    if (c0 + 3 < 72) {
      LOADAF(c0 + 3, afB);
      PACKC(c0 + 3, gB);
    }
    if (c0 + 5 < 72) GATHER(c0 + 5, gB);
    PHASE_BAR();
  }

  // epilogue: store C (col=lane&15 -> px, row=(lane>>4)*4+reg -> oc)
#pragma unroll
  for (int i = 0; i < 4; i++) {
    int ocB = wOc + i * 16 + quad * 4;
#pragma unroll
    for (int j = 0; j < 4; j++) {
      int px = pxt * 64 + j * 16 + ln;
#pragma unroll
      for (int r = 0; r < 4; r++)
        P.outf[((size_t)b * COUT + ocB + r) * Po + px] = acc[i][j][r];
    }
  }

  // fused stats: per-oc sum / sumsq (+ resize-weighted sum for high path)
  float pw[4];
  if (P.wsum) {
#pragma unroll
    for (int j = 0; j < 4; j++) {
      int px = pxt * 64 + j * 16 + ln;
      pw[j] = s_prof[px >> P.lWo] * s_prof[px & (P.Wo - 1)];
    }
  }
#pragma unroll
  for (int i = 0; i < 4; i++) {
    int ocB = wOc + i * 16 + quad * 4;
#pragma unroll
    for (int r = 0; r < 4; r++) {
      float s1 = 0.f, s2 = 0.f, sw = 0.f;
#pragma unroll
      for (int j = 0; j < 4; j++) {
        float v = acc[i][j][r];
        s1 += v;
        s2 += v * v;
        if (P.wsum) sw += v * pw[j];
      }
#pragma unroll
      for (int m = 1; m < 16; m <<= 1) {
        s1 += __shfl_xor(s1, m, 64);
        s2 += __shfl_xor(s2, m, 64);
        if (P.wsum) sw += __shfl_xor(sw, m, 64);
      }
      if (ln == 0) {
        atomicAdd(&P.sum[b * COUT + ocB + r], s1);
        atomicAdd(&P.sumsq[b * COUT + ocB + r], s2);
        if (P.wsum) atomicAdd(&P.wsum[b * COUT + ocB + r], sw);
      }
    }
  }
}

// ---------------------------------------------------------------------------
// All per-level scalar prep (GN affines, attention scalars, DyReLU MLP).
// One block per level (grid = 3).
// ---------------------------------------------------------------------------
struct PrepL {
  const float* st;  // 3584 floats: sumM,sqM,sumL,sqL,sumH,sqH,wsum
  float *Am, *Bm, *Al, *Bl, *Ah, *Bh, *svec, *coef;
  float invP, invPh, invn;
  int hasLow, hasHigh;
};
struct PrepB { PrepL L[3]; };

__global__ __launch_bounds__(256) void prep_all_kernel(
    PrepB PB, const float* __restrict__ g_mid, const float* __restrict__ be_mid,
    const float* __restrict__ g_low, const float* __restrict__ be_low,
    const float* __restrict__ g_high, const float* __restrict__ be_high,
    const float* __restrict__ w_sa, const float* __restrict__ b_sa,
    const float* __restrict__ w1, const float* __restrict__ b1,
    const float* __restrict__ w2, const float* __restrict__ b2) {
  __shared__ float s_m[3][NB][GN_GROUPS], s_iv[3][NB][GN_GROUPS];
  __shared__ float s_mean[3][NB][COUT];
  __shared__ float s_s[3][NB];
  __shared__ float s_nm[NB][COUT];
  __shared__ float s_h[NB][64];
  PrepL L = PB.L[blockIdx.x];
  const float* sumM = L.st;
  const float* sqM = L.st + 512;
  const float* sumL = L.st + 1024;
  const float* sqL = L.st + 1536;
  const float* sumH = L.st + 2048;
  const float* sqH = L.st + 2560;
  const float* swsum = L.st + 3072;
  int hasLow = L.hasLow, hasHigh = L.hasHigh;
  float invP = L.invP, invPh = L.invPh, invn = L.invn;
  int tid = threadIdx.x;

  if (tid < 96) {
    int path = tid / 32, b = (tid >> 4) & 1, g = tid & 15;
    int active = (path == 0) || (path == 1 && hasLow) || (path == 2 && hasHigh);
    if (active) {
      const float* su = path == 0 ? sumM : (path == 1 ? sumL : sumH);
      const float* sq = path == 0 ? sqM : (path == 1 ? sqL : sqH);
      float invN = ((path == 2) ? invPh : invP) * (1.f / 16.f);
      float s = 0.f, q = 0.f;
      for (int c = g * 16; c < g * 16 + 16; c++) {
        s += su[b * COUT + c];
        q += sq[b * COUT + c];
      }
      float m = s * invN;
      float v = q * invN - m * m;
      s_m[path][b][g] = m;
      s_iv[path][b][g] = rsqrtf(v + 1e-5f);
    }
  }
  __syncthreads();
  for (int idx = tid; idx < 3 * NB * COUT; idx += 256) {
    int path = idx / (NB * COUT);
    int r = idx % (NB * COUT);
    int b = r / COUT, c = r % COUT, g = c >> 4;
    int active = (path == 0) || (path == 1 && hasLow) || (path == 2 && hasHigh);
    if (active) {
      const float* ga = path == 0 ? g_mid : (path == 1 ? g_low : g_high);
      const float* be = path == 0 ? be_mid : (path == 1 ? be_low : be_high);
      float a = ga[c] * s_iv[path][b][g];
      float bb = be[c] - s_m[path][b][g] * a;
      float mean;
      if (path == 2)
        mean = a * (swsum[r] * invP) + bb;
      else {
        const float* su = path == 0 ? sumM : sumL;
        mean = a * (su[r] * invP) + bb;
      }
      float* Ad = path == 0 ? L.Am : (path == 1 ? L.Al : L.Ah);
      float* Bd = path == 0 ? L.Bm : (path == 1 ? L.Bl : L.Bh);
      Ad[r] = a;
      Bd[r] = bb;
      s_mean[path][b][c] = mean;
    }
  }
  __syncthreads();
  if (tid < 6) {
    int path = tid >> 1, b = tid & 1;
    int active = (path == 0) || (path == 1 && hasLow) || (path == 2 && hasHigh);
    float s = 0.f;
    if (active) {
      float t = 0.f;
      for (int c = 0; c < COUT; c++) t += s_mean[path][b][c] * w_sa[c];
      t += b_sa[0];
      t = fmaxf(t, 0.0f);
      s = fminf(fmaxf(t + 3.f, 0.f), 6.f) * (1.f / 6.f);
      L.svec[path * NB + b] = s;
    }
    s_s[path][b] = s;
  }
  __syncthreads();
  for (int idx = tid; idx < NB * COUT; idx += 256) {
    int b = idx / COUT, c = idx % COUT;
    float v = s_s[0][b] * s_mean[0][b][c];
    if (hasLow) v += s_s[1][b] * s_mean[1][b][c];
    if (hasHigh) v += s_s[2][b] * s_mean[2][b][c];
    s_nm[b][c] = v * invn;
  }
  __syncthreads();
  if (tid < NB * 64) {
    int b = tid / 64, j = tid % 64;
    float t = b1[j];
    for (int c = 0; c < COUT; c++) t += s_nm[b][c] * w1[j * COUT + c];
    s_h[b][j] = fmaxf(t, 0.f);
  }
  __syncthreads();
  for (int idx = tid; idx < NB * 1024; idx += 256) {
    int b = idx / 1024, i = idx % 1024;
    float t = b2[i];
    for (int j = 0; j < 64; j++) t += s_h[b][j] * w2[i * 64 + j];
    L.coef[idx] = fminf(fmaxf(t + 3.f, 0.f), 6.f) * (1.f / 6.f) - 0.5f;
  }
}

// ---------------------------------------------------------------------------
// Fused epilogue: GN-affine+scale of mid (+low) (+bilinear-resized high),
// then DyReLU. All three levels in one launch; float4 / 4 px per thread.
// ---------------------------------------------------------------------------
struct ApL {
  const float* featM; const float* featL; const float* featH;
  const float* Am; const float* Bm; const float* Al; const float* Bl;
  const float* Ah; const float* Bh; const float* svec; const float* coef;
  float* out;
  int lP, lHo, Hh, hasLow, hasHigh;
  float invn;
};
struct ApB { ApL L[3]; int off[4]; };

__global__ __launch_bounds__(256) void fused_apply_kernel(ApB A) {
  int bx = blockIdx.x;
  int li = (bx >= A.off[1] ? 1 : 0) + (bx >= A.off[2] ? 1 : 0);
  ApL L = A.L[li];
  int idx = ((bx - A.off[li]) * 256 + threadIdx.x) * 4;
  int bc = idx >> L.lP;
  int p0 = idx & ((1 << L.lP) - 1);
  int b = bc >> 8, c = bc & 255;
  float am = L.Am[bc], bm = L.Bm[bc], sm = L.svec[b];
  float4 fm = *(const float4*)&L.featM[idx];
  float v0 = (fm.x * am + bm) * sm;
  float v1 = (fm.y * am + bm) * sm;
  float v2 = (fm.z * am + bm) * sm;
  float v3 = (fm.w * am + bm) * sm;
  if (L.hasLow) {
    float al = L.Al[bc], bl = L.Bl[bc], sl = L.svec[2 + b];
    float4 fl = *(const float4*)&L.featL[idx];
    v0 += (fl.x * al + bl) * sl;
    v1 += (fl.y * al + bl) * sl;
    v2 += (fl.z * al + bl) * sl;
    v3 += (fl.w * al + bl) * sl;
  }
  if (L.hasHigh) {
    int Ho = 1 << L.lHo;
    int Y = p0 >> L.lHo, X0 = p0 & (Ho - 1);  // 4 px share one row
    float r = (float)(L.Hh - 1) / (float)(Ho - 1);
    float sy = (float)Y * r;
    int yl = (int)floorf(sy);
    int yh = min(yl + 1, L.Hh - 1);
    float wy = sy - (float)yl;
    float ah = L.Ah[bc], bh = L.Bh[bc], sh = L.svec[4 + b];
    const float* fp = L.featH + (size_t)bc * L.Hh * L.Hh;
    const float* fpl = fp + yl * L.Hh;
    const float* fph = fp + yh * L.Hh;
    float hv[4];
#pragma unroll
    for (int j = 0; j < 4; j++) {
      float sx = (float)(X0 + j) * r;
      int xl = (int)floorf(sx);
      int xh = min(xl + 1, L.Hh - 1);
      float wx = sx - (float)xl;
      float t0 = fpl[xl] * (1.f - wx) + fpl[xh] * wx;
      float t1 = fph[xl] * (1.f - wx) + fph[xh] * wx;
      hv[j] = ((t0 * (1.f - wy) + t1 * wy) * ah + bh) * sh;
    }
    v0 += hv[0]; v1 += hv[1]; v2 += hv[2]; v3 += hv[3];
  }
  float a1 = L.coef[b * 1024 + c] * 2.f + 1.f;
  float b1v = L.coef[b * 1024 + 256 + c];
  float a2 = L.coef[b * 1024 + 512 + c] * 2.f;
  float b2v = L.coef[b * 1024 + 768 + c];
  float4 o;
  float x0 = v0 * L.invn, x1 = v1 * L.invn, x2 = v2 * L.invn, x3 = v3 * L.invn;
  o.x = fmaxf(x0 * a1 + b1v, x0 * a2 + b2v);
  o.y = fmaxf(x1 * a1 + b1v, x1 * a2 + b2v);
  o.z = fmaxf(x2 * a1 + b1v, x2 * a2 + b2v);
  o.w = fmaxf(x3 * a1 + b1v, x3 * a2 + b2v);
  *(float4*)&L.out[idx] = o;
}

// ---------------------------------------------------------------------------
extern "C" void kernel_launch(void* const* d_in, const int* in_sizes, int n_in,
                              void* d_out, int out_size, void* d_ws,
                              size_t ws_size, hipStream_t stream) {
  (void)in_sizes; (void)n_in; (void)out_size; (void)ws_size;
  const float* x[3] = {(const float*)d_in[0], (const float*)d_in[1],
                       (const float*)d_in[2]};
  const float* w_off = (const float*)d_in[3];
  const float* b_off = (const float*)d_in[4];
  const float* w_mid = (const float*)d_in[5];
  const float* g_mid = (const float*)d_in[6];
  const float* be_mid = (const float*)d_in[7];
  const float* w_low = (const float*)d_in[8];
  const float* g_low = (const float*)d_in[9];
  const float* be_low = (const float*)d_in[10];
  const float* w_high = (const float*)d_in[11];
  const float* g_high = (const float*)d_in[12];
  const float* be_high = (const float*)d_in[13];
  const float* w_sa = (const float*)d_in[14];
  const float* b_sa = (const float*)d_in[15];
  const float* w_dy1 = (const float*)d_in[16];
  const float* b_dy1 = (const float*)d_in[17];
  const float* w_dy2 = (const float*)d_in[18];
  const float* b_dy2 = (const float*)d_in[19];

  float* out = (float*)d_out;
  char* wsb = (char*)d_ws;
  size_t o = 0;
  unsigned short* xT0 = (unsigned short*)(wsb + o); o += 16777216;
  unsigned short* xT1 = (unsigned short*)(wsb + o); o += 4194304;
  unsigned short* xT2 = (unsigned short*)(wsb + o); o += 1048576;
  unsigned short* wtm = (unsigned short*)(wsb + o); o += 1179648;
  unsigned short* wtl = (unsigned short*)(wsb + o); o += 1179648;
  unsigned short* wth = (unsigned short*)(wsb + o); o += 1179648;
  unsigned short* wo  = (unsigned short*)(wsb + o); o += 294912;
  float* om0 = (float*)(wsb + o); o += 3538944;
  float* om1 = (float*)(wsb + o); o += 884736;
  float* om2 = (float*)(wsb + o); o += 221184;
  float* arena = (float*)(wsb + o); o += 65011712;  // all levels' feats
  float* stats = (float*)(wsb + o); o += 43072;     // 3x3584 floats
  float* Am = (float*)(wsb + o); o += 6144;         // 3 x 512 floats each
  float* Bm = (float*)(wsb + o); o += 6144;
  float* Al = (float*)(wsb + o); o += 6144;
  float* Bl = (float*)(wsb + o); o += 6144;
  float* Ah = (float*)(wsb + o); o += 6144;
  float* Bh = (float*)(wsb + o); o += 6144;
  float* svec = (float*)(wsb + o); o += 192;        // 3 x 16 floats
  float* dycoef = (float*)(wsb + o); o += 24576;    // 3 x 2048 floats

  // per-level feature buffers (floats), all live simultaneously
  float* featM0 = arena;                  // 2*256*16384
  float* featH0 = arena + 8388608;        // 2*256*4096
  float* featM1 = arena + 10485760;       // 2*256*4096
  float* featL1 = arena + 12582912;       // 2*256*4096
  float* featH1 = arena + 14680064;       // 2*256*1024
  float* featM2 = arena + 15204352;       // 2*256*1024
  float* featL2 = arena + 15728640;       // 2*256*1024

  // x_lo scratch aliases the arena (consumed by conv_offset before any
  // mdconv writes feats).
  unsigned short* xLo0 = (unsigned short*)arena;
  unsigned short* xLo1 = xLo0 + 8388608;
  unsigned short* xLo2 = xLo1 + 2097152;

  // One setup launch: transposes + weight repacks + stats zeroing.
  SetB sb = {x[0], x[1], x[2], w_mid, w_low, w_high, w_off,
             xT0, xT1, xT2, xLo0, xLo1, xLo2, wtm, wtl, wth, wo, stats};
  setup_kernel<<<10219, 256, 0, stream>>>(sb);

  // Batched offset conv over all 3 levels.
  CoB cob;
  cob.L[0] = {xT0, xLo0, om0, 128, 128, 64, 6, 1, 16384};
  cob.L[1] = {xT1, xLo1, om1, 64, 64, 64, 6, 1, 4096};
  cob.L[2] = {xT2, xLo2, om2, 32, 32, 32, 5, 2, 1024};
  cob.off[0] = 0; cob.off[1] = 512; cob.off[2] = 640; cob.off[3] = 672;
  conv_offset_kernel<<<672, 256, 0, stream>>>(cob, wo, b_off);

  // All 7 mdconv paths (3 levels) in one launch; biggest first.
  float* S0 = stats;
  float* S1 = stats + 3584;
  float* S2 = stats + 7168;
  MdBatch mb;
  mb.p[0] = {xT0, wtm, featM0, om0, S0, S0 + 512, nullptr,
             128, 128, 128, 7, 1, 1, 128, 16384, 8, 0};          // l0 mid 512
  mb.p[1] = {xT1, wth, featH0, om0, S0 + 2048, S0 + 2560, S0 + 3072,
             64, 64, 64, 6, 1, 2, 128, 16384, 6, 128};           // l0 high 128
  mb.p[2] = {xT1, wtm, featM1, om1, S1, S1 + 512, nullptr,
             64, 64, 64, 6, 1, 1, 64, 4096, 6, 0};               // l1 mid 128
  mb.p[3] = {xT0, wtl, featL1, om1, S1 + 1024, S1 + 1536, nullptr,
             128, 128, 64, 6, 2, 1, 64, 4096, 6, 0};             // l1 low 128
  mb.p[4] = {xT2, wth, featH1, om1, S1 + 2048, S1 + 2560, S1 + 3072,
             32, 32, 32, 5, 1, 2, 64, 4096, 4, 64};              // l1 high 32
  mb.p[5] = {xT2, wtm, featM2, om2, S2, S2 + 512, nullptr,
             32, 32, 32, 5, 1, 1, 32, 1024, 4, 0};               // l2 mid 32
  mb.p[6] = {xT1, wtl, featL2, om2, S2 + 1024, S2 + 1536, nullptr,
             64, 64, 32, 5, 2, 1, 32, 1024, 4, 0};               // l2 low 32
  mb.off[0] = 0;   mb.off[1] = 512; mb.off[2] = 640; mb.off[3] = 768;
  mb.off[4] = 896; mb.off[5] = 928; mb.off[6] = 960;
  mdconv_kernel<<<992, 256, 0, stream>>>(mb);

  // Per-level scalar prep: one block per level.
  PrepB pb;
  {
    const int Hs[3] = {128, 64, 32};
    const float nterm[3] = {2.f, 3.f, 2.f};
    for (int l = 0; l < 3; l++) {
      int H = Hs[l];
      int Pp = H * H;
      int Ph = (H / 2) * (H / 2);
      pb.L[l] = {stats + l * 3584, Am + l * 512, Bm + l * 512, Al + l * 512,
                 Bl + l * 512, Ah + l * 512, Bh + l * 512, svec + l * 16,
                 dycoef + l * 2048, 1.0f / (float)Pp, 1.0f / (float)Ph,
                 1.0f / nterm[l], l > 0 ? 1 : 0, l < 2 ? 1 : 0};
    }
  }
  prep_all_kernel<<<3, 256, 0, stream>>>(pb, g_mid, be_mid, g_low, be_low,
                                         g_high, be_high, w_sa, b_sa, w_dy1,
                                         b_dy1, w_dy2, b_dy2);

  // Fused epilogue, all levels in one launch; 4 px per thread.
  ApB ab;
  ab.L[0] = {featM0, featM0, featH0, Am, Bm, Al, Bl, Ah, Bh, svec, dycoef,
             out, 14, 7, 64, 0, 1, 0.5f};
  ab.L[1] = {featM1, featL1, featH1, Am + 512, Bm + 512, Al + 512, Bl + 512,
             Ah + 512, Bh + 512, svec + 16, dycoef + 2048, out + 8388608,
             12, 6, 32, 1, 1, 1.0f / 3.0f};
  ab.L[2] = {featM2, featL2, featM2, Am + 1024, Bm + 1024, Al + 1024,
             Bl + 1024, Ah + 1024, Bh + 1024, svec + 32, dycoef + 4096,
             out + 10485760, 10, 5, 16, 1, 0, 0.5f};
  ab.off[0] = 0; ab.off[1] = 8192; ab.off[2] = 10240; ab.off[3] = 10752;
  fused_apply_kernel<<<10752, 256, 0, stream>>>(ab);
}